// Round 14
// baseline (284.440 us; speedup 1.0000x reference)
//
#include <hip/hip_runtime.h>
#include <hip/hip_bf16.h>
#include <stdint.h>

#define B_ 2
#define N_ 4096
#define D_ 128
#define H_ 4
#define HID_ 32
#define EN_ 16
#define ALPHA_ 0.2f
#define S1_ 4
#define LOG2E_ 1.4426950408889634f

typedef __attribute__((ext_vector_type(8))) _Float16 f16x8;
typedef __attribute__((ext_vector_type(4))) float f32x4;
typedef __attribute__((ext_vector_type(8))) unsigned short u16x8;

__device__ __forceinline__ unsigned short f2h(float v) {
    _Float16 h = (_Float16)v;
    return *(unsigned short*)&h;
}

// ---------- fused prep: blocks [0,2048) = adj->bitmask; [2048,3072) = layer-1 proj.
__global__ __launch_bounds__(256) void prep_kernel(
    const float* __restrict__ adj, unsigned long long* __restrict__ mask,
    const float* __restrict__ fea, const float* __restrict__ Wh,
    const float* __restrict__ a_heads,
    float* __restrict__ wh1, float* __restrict__ wh2,
    float* __restrict__ cmax1, unsigned short* __restrict__ whTt)
{
    __shared__ float xs[32][132];
    __shared__ float WT[32][132];
    __shared__ float Wa[2][128];
    __shared__ float as_[2 * HID_];
    __shared__ unsigned short ts[32][32];
    __shared__ float rmax[32];
    const int tid = threadIdx.x;

    if (blockIdx.x < 2048) {               // ---- mask part ----
        const int b = blockIdx.x >> 10, ib = blockIdx.x & 1023;
        const int i = ib * 4 + (tid >> 6);
        const int lane = tid & 63;
        const float* ar = adj + ((size_t)b * N_ + i) * N_;
        unsigned long long* mrow = mask + ((size_t)b * N_ + i) * 64;
#pragma unroll 4
        for (int c = 0; c < 16; ++c) {
            float4 v = *(const float4*)(ar + c * 256 + lane * 4);
            unsigned long long b0 = __ballot(v.x != 0.f);
            unsigned long long b1 = __ballot(v.y != 0.f);
            unsigned long long b2 = __ballot(v.z != 0.f);
            unsigned long long b3 = __ballot(v.w != 0.f);
            if (lane == 0) {
                ulonglong2 w01 = {b0, b1}, w23 = {b2, b3};
                *(ulonglong2*)(mrow + c * 4) = w01;
                *(ulonglong2*)(mrow + c * 4 + 2) = w23;
            }
        }
        return;
    }
    // ---- proj1 part: 32 rows x 32 cols, one head ----
    const int l0 = blockIdx.x - 2048;
    const int ib = l0 & 127, h = (l0 >> 7) & 3, b = l0 >> 9;
    const int i0 = ib * 32;
    const float* Wp = Wh + (size_t)h * D_ * HID_;
    for (int l = tid; l < 1024; l += 256) {
        float4 w4 = *(const float4*)(Wp + l * 4);
        int k = l >> 3, d = (l & 7) * 4;
        WT[d][k] = w4.x; WT[d + 1][k] = w4.y; WT[d + 2][k] = w4.z; WT[d + 3][k] = w4.w;
    }
    if (tid < 2 * HID_) as_[tid] = a_heads[h * 2 * HID_ + tid];
    const float* xp = fea + ((size_t)b * N_ + i0) * D_;
    for (int l = tid; l < 1024; l += 256) {
        int r = l >> 5, k4 = (l & 31) * 4;
        *(float4*)&xs[r][k4] = *(const float4*)(xp + r * D_ + k4);
    }
    __syncthreads();
    {
        const int k = tid & 127, j = tid >> 7;
        const float* wr = Wp + k * HID_;
        const float* aw = &as_[j * HID_];
        float s = 0.f;
#pragma unroll
        for (int d = 0; d < HID_; d += 4) {
            float4 w4 = *(const float4*)(wr + d);
            s += w4.x * aw[d] + w4.y * aw[d + 1] + w4.z * aw[d + 2] + w4.w * aw[d + 3];
        }
        Wa[j][k] = s;
    }
    const int c = tid & 15, rg = (tid >> 4) * 2;
    float a0[2] = {0.f, 0.f}, a1[2] = {0.f, 0.f};
#pragma unroll 8
    for (int k = 0; k < D_; k += 4) {
        float4 w0 = *(float4*)&WT[c][k];
        float4 w1 = *(float4*)&WT[c + 16][k];
#pragma unroll
        for (int i = 0; i < 2; ++i) {
            float4 x4 = *(float4*)&xs[rg + i][k];
            a0[i] += x4.x * w0.x + x4.y * w0.y + x4.z * w0.z + x4.w * w0.w;
            a1[i] += x4.x * w1.x + x4.y * w1.y + x4.z * w1.z + x4.w * w1.w;
        }
    }
#pragma unroll
    for (int i = 0; i < 2; ++i) {
        ts[c][rg + i] = f2h(a0[i]);
        ts[c + 16][rg + i] = f2h(a1[i]);
    }
    __syncthreads();
    {
        const int row = tid >> 3, q = tid & 7;
        float d1 = 0.f, d2 = 0.f;
#pragma unroll
        for (int k = q * 16; k < q * 16 + 16; k += 4) {
            float4 x4 = *(float4*)&xs[row][k];
            float4 u = *(float4*)&Wa[0][k];
            float4 v = *(float4*)&Wa[1][k];
            d1 += x4.x * u.x + x4.y * u.y + x4.z * u.z + x4.w * u.w;
            d2 += x4.x * v.x + x4.y * v.y + x4.z * v.z + x4.w * v.w;
        }
        d1 += __shfl_xor(d1, 1); d1 += __shfl_xor(d1, 2); d1 += __shfl_xor(d1, 4);
        d2 += __shfl_xor(d2, 1); d2 += __shfl_xor(d2, 2); d2 += __shfl_xor(d2, 4);
        if (q == 0) {
            const size_t o = (size_t)(b * H_ + h) * N_ + i0 + row;
            wh1[o] = d1 * LOG2E_;
            wh2[o] = d2 * LOG2E_;
            rmax[row] = d2 * LOG2E_;
        }
    }
    __syncthreads();
    if (tid < 128) {
        const int d = tid >> 2, part = (tid & 3) * 8;
        unsigned short* dst = whTt + ((size_t)(b * H_ + h) * 64 + (i0 >> 6)) * 2048
                            + d * 64 + (i0 & 63) + part;
        *(u16x8*)dst = *(u16x8*)&ts[d][part];
    }
    if (tid < 32) {
        float mx = rmax[tid];
#pragma unroll
        for (int off = 16; off; off >>= 1) mx = fmaxf(mx, __shfl_xor(mx, off));
        if (tid == 0) cmax1[(size_t)(b * H_ + h) * 128 + ib] = mx;
    }
}

// ---------- layer-1 fused MFMA attention (unchanged from R13)
__global__ __launch_bounds__(256, 4) void attn1_kernel(
    const unsigned long long* __restrict__ mask, const unsigned short* __restrict__ whT,
    const float* __restrict__ wh1, const float* __restrict__ wh2,
    const float* __restrict__ cmax1,
    float* __restrict__ x2p, float* __restrict__ l1p)
{
    __shared__ unsigned long long mask_s[32][17];
    const int b = blockIdx.z, split = blockIdx.y, i0 = blockIdx.x * 32;
    const int tid = threadIdx.x, lane = tid & 63, h = tid >> 6;
    const int m = lane & 15, quad = lane >> 4;
    {
        const int r = tid >> 3, w = (tid & 7) * 2;
        ulonglong2 mw = *(const ulonglong2*)(mask + ((size_t)b * N_ + i0 + r) * 64
                                             + split * 16 + w);
        mask_s[r][w] = mw.x; mask_s[r][w + 1] = mw.y;
    }
    const float* cm = cmax1 + (size_t)(b * H_ + h) * 128;
    float Mh = fmaxf(cm[lane], cm[lane + 64]);
#pragma unroll
    for (int off = 32; off; off >>= 1) Mh = fmaxf(Mh, __shfl_xor(Mh, off));
    const size_t bhN = (size_t)(b * H_ + h) * N_;
    const float w1r0 = wh1[bhN + i0 + m];
    const float w1r1 = wh1[bhN + i0 + 16 + m];
    const float sb0 = w1r0 + Mh, sb1 = w1r1 + Mh;
    const float mr0 = fmaxf(sb0, ALPHA_ * sb0);
    const float mr1 = fmaxf(sb1, ALPHA_ * sb1);
    const float* wvb = wh2 + bhN + split * 1024 + quad * 8;
    const unsigned short* bpb = whT + (size_t)(b * H_ + h) * 131072
                              + (size_t)split * 16 * 2048 + m * 64 + quad * 8;
    f32x4 a00 = {0.f,0.f,0.f,0.f}, a01 = {0.f,0.f,0.f,0.f}, a02 = {0.f,0.f,0.f,0.f};
    f32x4 a10 = {0.f,0.f,0.f,0.f}, a11 = {0.f,0.f,0.f,0.f}, a12 = {0.f,0.f,0.f,0.f};
    f16x8 ones;
#pragma unroll
    for (int q = 0; q < 8; ++q) ones[q] = (_Float16)1.0f;
    __syncthreads();

    for (int c = 0; c < 4; ++c) {
        const unsigned long long P0 = mask_s[m][c*4+0], P1 = mask_s[m][c*4+1];
        const unsigned long long P2 = mask_s[m][c*4+2], P3 = mask_s[m][c*4+3];
        const unsigned long long Q0 = mask_s[m+16][c*4+0], Q1 = mask_s[m+16][c*4+1];
        const unsigned long long Q2 = mask_s[m+16][c*4+2], Q3 = mask_s[m+16][c*4+3];
#pragma unroll
        for (int q4 = 0; q4 < 4; ++q4) {
            const int t = c * 4 + q4;
            const unsigned short* bp = bpb + (size_t)t * 2048;
            f16x8 b00 = *(const f16x8*)bp;
            f16x8 b10 = *(const f16x8*)(bp + 32);
            f16x8 b01 = *(const f16x8*)(bp + 1024);
            f16x8 b11 = *(const f16x8*)(bp + 1056);
            const float* nw = wvb + t * 64;
            float4 u0 = *(const float4*)nw;
            float4 u1 = *(const float4*)(nw + 4);
            float4 v0 = *(const float4*)(nw + 32);
            float4 v1 = *(const float4*)(nw + 36);
#pragma unroll
            for (int ks = 0; ks < 2; ++ks) {
                const int sh = 16 * q4 + 8 * ks + 2 * quad;
                float wv8[8];
                if (ks == 0) { *(float4*)&wv8[0] = u0; *(float4*)&wv8[4] = u1; }
                else         { *(float4*)&wv8[0] = v0; *(float4*)&wv8[4] = v1; }
                const unsigned int gp0 = (unsigned int)(P0 >> sh) & 3u;
                const unsigned int gp1 = (unsigned int)(P1 >> sh) & 3u;
                const unsigned int gp2 = (unsigned int)(P2 >> sh) & 3u;
                const unsigned int gp3 = (unsigned int)(P3 >> sh) & 3u;
                const unsigned int gq0 = (unsigned int)(Q0 >> sh) & 3u;
                const unsigned int gq1 = (unsigned int)(Q1 >> sh) & 3u;
                const unsigned int gq2 = (unsigned int)(Q2 >> sh) & 3u;
                const unsigned int gq3 = (unsigned int)(Q3 >> sh) & 3u;
                f16x8 af0, af1;
#pragma unroll
                for (int qq = 0; qq < 4; ++qq) {
                    float r0p[2], r1p[2];
#pragma unroll
                    for (int cc = 0; cc < 2; ++cc) {
                        const int jj = qq * 2 + cc;
                        const unsigned int bsel = 1u << (jj >> 2);
                        const unsigned int gp = (jj&3)==0?gp0:(jj&3)==1?gp1:(jj&3)==2?gp2:gp3;
                        const unsigned int gq = (jj&3)==0?gq0:(jj&3)==1?gq1:(jj&3)==2?gq2:gq3;
                        float s0 = w1r0 + wv8[jj];
                        float e0 = fmaxf(s0, ALPHA_ * s0);
                        float t0 = ((gp & bsel) == 0u || s0 == 0.f) ? -1e38f : (e0 - mr0);
                        r0p[cc] = __builtin_amdgcn_exp2f(t0);
                        float s1 = w1r1 + wv8[jj];
                        float e1 = fmaxf(s1, ALPHA_ * s1);
                        float t1 = ((gq & bsel) == 0u || s1 == 0.f) ? -1e38f : (e1 - mr1);
                        r1p[cc] = __builtin_amdgcn_exp2f(t1);
                    }
                    auto pr0 = __builtin_amdgcn_cvt_pkrtz(r0p[0], r0p[1]);
                    af0[qq*2] = (_Float16)pr0[0]; af0[qq*2+1] = (_Float16)pr0[1];
                    auto pr1 = __builtin_amdgcn_cvt_pkrtz(r1p[0], r1p[1]);
                    af1[qq*2] = (_Float16)pr1[0]; af1[qq*2+1] = (_Float16)pr1[1];
                }
                f16x8 bb0 = ks ? b10 : b00;
                f16x8 bb1 = ks ? b11 : b01;
                a00 = __builtin_amdgcn_mfma_f32_16x16x32_f16(af0, bb0, a00, 0, 0, 0);
                a01 = __builtin_amdgcn_mfma_f32_16x16x32_f16(af0, bb1, a01, 0, 0, 0);
                a02 = __builtin_amdgcn_mfma_f32_16x16x32_f16(af0, ones, a02, 0, 0, 0);
                a10 = __builtin_amdgcn_mfma_f32_16x16x32_f16(af1, bb0, a10, 0, 0, 0);
                a11 = __builtin_amdgcn_mfma_f32_16x16x32_f16(af1, bb1, a11, 0, 0, 0);
                a12 = __builtin_amdgcn_mfma_f32_16x16x32_f16(af1, ones, a12, 0, 0, 0);
            }
        }
    }
    float* xp = x2p + (((size_t)split * B_ + b) * N_ + i0) * D_ + h * HID_;
#pragma unroll
    for (int reg = 0; reg < 4; ++reg) {
        const int row = quad * 4 + reg;
        xp[(size_t)row * D_ + m] = a00[reg];
        xp[(size_t)row * D_ + 16 + m] = a01[reg];
        xp[(size_t)(row + 16) * D_ + m] = a10[reg];
        xp[(size_t)(row + 16) * D_ + 16 + m] = a11[reg];
    }
    if (m == 0) {
        float* lp = l1p + (((size_t)split * B_ + b) * N_ + i0) * H_ + h;
#pragma unroll
        for (int reg = 0; reg < 4; ++reg) {
            lp[(size_t)(quad * 4 + reg) * H_] = a02[reg];
            lp[(size_t)(quad * 4 + reg + 16) * H_] = a12[reg];
        }
    }
}

// ---------- merged layer-2 projection (unchanged from R13)
__global__ __launch_bounds__(256) void proj2_kernel(
    const float* __restrict__ x2p, const float* __restrict__ l1p,
    const float* __restrict__ Wl, const float* __restrict__ a_last,
    float* __restrict__ wh1b, float* __restrict__ wh2b,
    float* __restrict__ cmax2, unsigned short* __restrict__ whT2t)
{
    __shared__ float Ws[D_ * EN_];
    __shared__ float xs[16][D_];
    __shared__ float as_[2 * EN_];
    __shared__ unsigned short ts[EN_][16];
    __shared__ float rmax[16];
    const int b = blockIdx.y, i0 = blockIdx.x * 16, tid = threadIdx.x;
    for (int idx = tid * 4; idx < D_ * EN_; idx += 1024)
        *(float4*)&Ws[idx] = *(const float4*)(Wl + idx);
    if (tid < 2 * EN_) as_[tid] = a_last[tid];
    for (int idx = tid * 4; idx < 16 * D_; idx += 1024) {
        const int r = idx >> 7, hd = idx & 127, h = hd >> 5;
        float4 v = {0.f, 0.f, 0.f, 0.f};
        float l = 0.f;
#pragma unroll
        for (int s = 0; s < S1_; ++s) {
            const size_t gi = ((size_t)s * B_ + b) * N_ + i0 + r;
            float4 p = *(const float4*)(x2p + gi * D_ + hd);
            v.x += p.x; v.y += p.y; v.z += p.z; v.w += p.w;
            l += l1p[gi * H_ + h];
        }
        float linv = 1.f / fmaxf(l, 1e-30f);
        float o0 = v.x * linv, o1 = v.y * linv, o2 = v.z * linv, o3 = v.w * linv;
        xs[r][hd]     = o0 > 0.f ? o0 : expm1f(o0);
        xs[r][hd + 1] = o1 > 0.f ? o1 : expm1f(o1);
        xs[r][hd + 2] = o2 > 0.f ? o2 : expm1f(o2);
        xs[r][hd + 3] = o3 > 0.f ? o3 : expm1f(o3);
    }
    __syncthreads();
    const int r = tid >> 4, e = tid & 15;
    float acc = 0.f;
#pragma unroll 8
    for (int k = 0; k < D_; ++k) acc += xs[r][k] * Ws[k * EN_ + e];
    ts[e][r] = f2h(acc);
    float d1 = acc * as_[e], d2 = acc * as_[EN_ + e];
#pragma unroll
    for (int off = 8; off; off >>= 1) {
        d1 += __shfl_xor(d1, off);
        d2 += __shfl_xor(d2, off);
    }
    d1 *= LOG2E_; d2 *= LOG2E_;
    if (e == 0) {
        wh1b[(size_t)b * N_ + i0 + r] = d1;
        wh2b[(size_t)b * N_ + i0 + r] = d2;
        rmax[r] = d2;
    }
    __syncthreads();
    if (tid < EN_) {
        unsigned short* dst = whT2t + (size_t)b * 65536
                            + (i0 >> 6) * 1024 + tid * 64 + (i0 & 63);
        *(u16x8*)dst = *(u16x8*)&ts[tid][0];
        *(u16x8*)(dst + 8) = *(u16x8*)&ts[tid][8];
    }
    if (tid == 0) {
        float mx = rmax[0];
#pragma unroll
        for (int k = 1; k < 16; ++k) mx = fmaxf(mx, rmax[k]);
        cmax2[(size_t)b * 256 + blockIdx.x] = mx;
    }
}

// ---------- layer-2 attention + finalize fused: block 512 = 8 waves, 32 rows,
// each wave covers 512 j (8 tiles, 2 row-groups share fragments), 8-wave LDS
// combine, divide + ELU, final store. No partials, no separate finalize.
__global__ __launch_bounds__(512) void attn2f_kernel(
    const unsigned long long* __restrict__ mask, const unsigned short* __restrict__ whT2,
    const float* __restrict__ wh1b, const float* __restrict__ wh2b,
    const float* __restrict__ cmax2, float* __restrict__ out)
{
    __shared__ unsigned long long mask_s[32][66];   // 32 rows x 64 words, 16.5 KB
    __shared__ float accred[8][32][17];             // 18.7 KB
    __shared__ float lred[8][32];
    const int b = blockIdx.y, i0 = blockIdx.x * 32;
    const int tid = threadIdx.x, lane = tid & 63, wv = tid >> 6;
    const int m = lane & 15, quad = lane >> 4;
    {
        const int r = tid >> 4, w = (tid & 15) * 4;
        const unsigned long long* src = mask + ((size_t)b * N_ + i0 + r) * 64 + w;
        ulonglong2 m0 = *(const ulonglong2*)src;
        ulonglong2 m1 = *(const ulonglong2*)(src + 2);
        mask_s[r][w] = m0.x; mask_s[r][w + 1] = m0.y;
        mask_s[r][w + 2] = m1.x; mask_s[r][w + 3] = m1.y;
    }
    const float* cm = cmax2 + (size_t)b * 256;
    float4 c0 = *(const float4*)(cm + lane * 4);
    float Mh = fmaxf(fmaxf(c0.x, c0.y), fmaxf(c0.z, c0.w));
#pragma unroll
    for (int off = 32; off; off >>= 1) Mh = fmaxf(Mh, __shfl_xor(Mh, off));
    const float w1r0 = wh1b[(size_t)b * N_ + i0 + m];
    const float w1r1 = wh1b[(size_t)b * N_ + i0 + 16 + m];
    const float sb0 = w1r0 + Mh, sb1 = w1r1 + Mh;
    const float mr0 = fmaxf(sb0, ALPHA_ * sb0);
    const float mr1 = fmaxf(sb1, ALPHA_ * sb1);
    const unsigned short* wTg = whT2 + (size_t)b * 65536 + m * 64 + quad * 8;
    const float* w2g = wh2b + (size_t)b * N_ + quad * 8;
    f32x4 a0 = {0.f,0.f,0.f,0.f}, a1 = {0.f,0.f,0.f,0.f};
    f32x4 l0 = {0.f,0.f,0.f,0.f}, l1 = {0.f,0.f,0.f,0.f};
    f16x8 ones;
#pragma unroll
    for (int q = 0; q < 8; ++q) ones[q] = (_Float16)1.0f;
    __syncthreads();

#pragma unroll
    for (int cc = 0; cc < 2; ++cc) {                 // wave's 2 chunks of 256 j
        const int ch = wv * 2 + cc;
        const unsigned long long P0 = mask_s[m][ch*4+0], P1 = mask_s[m][ch*4+1];
        const unsigned long long P2 = mask_s[m][ch*4+2], P3 = mask_s[m][ch*4+3];
        const unsigned long long Q0 = mask_s[m+16][ch*4+0], Q1 = mask_s[m+16][ch*4+1];
        const unsigned long long Q2 = mask_s[m+16][ch*4+2], Q3 = mask_s[m+16][ch*4+3];
#pragma unroll
        for (int q4 = 0; q4 < 4; ++q4) {
            const int jb = ch * 4 + q4;
            const unsigned short* bp = wTg + (size_t)jb * 1024;
            f16x8 cb0 = *(const f16x8*)(bp);
            f16x8 cb1 = *(const f16x8*)(bp + 32);
            const float* nw = w2g + jb * 64;
            float4 u0 = *(const float4*)(nw);
            float4 u1 = *(const float4*)(nw + 4);
            float4 v0 = *(const float4*)(nw + 32);
            float4 v1 = *(const float4*)(nw + 36);
#pragma unroll
            for (int ks = 0; ks < 2; ++ks) {
                const int sh = 16 * q4 + 8 * ks + 2 * quad;
                float wv8[8];
                if (ks == 0) { *(float4*)&wv8[0] = u0; *(float4*)&wv8[4] = u1; }
                else         { *(float4*)&wv8[0] = v0; *(float4*)&wv8[4] = v1; }
                const unsigned int gp0 = (unsigned int)(P0 >> sh) & 3u;
                const unsigned int gp1 = (unsigned int)(P1 >> sh) & 3u;
                const unsigned int gp2 = (unsigned int)(P2 >> sh) & 3u;
                const unsigned int gp3 = (unsigned int)(P3 >> sh) & 3u;
                const unsigned int gq0 = (unsigned int)(Q0 >> sh) & 3u;
                const unsigned int gq1 = (unsigned int)(Q1 >> sh) & 3u;
                const unsigned int gq2 = (unsigned int)(Q2 >> sh) & 3u;
                const unsigned int gq3 = (unsigned int)(Q3 >> sh) & 3u;
                f16x8 af0, af1;
#pragma unroll
                for (int qq = 0; qq < 4; ++qq) {
                    float r0p[2], r1p[2];
#pragma unroll
                    for (int c2 = 0; c2 < 2; ++c2) {
                        const int jj = qq * 2 + c2;
                        const unsigned int bsel = 1u << (jj >> 2);
                        const unsigned int gp = (jj&3)==0?gp0:(jj&3)==1?gp1:(jj&3)==2?gp2:gp3;
                        const unsigned int gq = (jj&3)==0?gq0:(jj&3)==1?gq1:(jj&3)==2?gq2:gq3;
                        float s0 = w1r0 + wv8[jj];
                        float e0 = fmaxf(s0, ALPHA_ * s0);
                        float t0 = ((gp & bsel) == 0u || s0 == 0.f) ? -1e38f : (e0 - mr0);
                        r0p[c2] = __builtin_amdgcn_exp2f(t0);
                        float s1 = w1r1 + wv8[jj];
                        float e1 = fmaxf(s1, ALPHA_ * s1);
                        float t1 = ((gq & bsel) == 0u || s1 == 0.f) ? -1e38f : (e1 - mr1);
                        r1p[c2] = __builtin_amdgcn_exp2f(t1);
                    }
                    auto pr0 = __builtin_amdgcn_cvt_pkrtz(r0p[0], r0p[1]);
                    af0[qq*2] = (_Float16)pr0[0]; af0[qq*2+1] = (_Float16)pr0[1];
                    auto pr1 = __builtin_amdgcn_cvt_pkrtz(r1p[0], r1p[1]);
                    af1[qq*2] = (_Float16)pr1[0]; af1[qq*2+1] = (_Float16)pr1[1];
                }
                f16x8 bb = ks ? cb1 : cb0;
                a0 = __builtin_amdgcn_mfma_f32_16x16x32_f16(af0, bb, a0, 0, 0, 0);
                l0 = __builtin_amdgcn_mfma_f32_16x16x32_f16(af0, ones, l0, 0, 0, 0);
                a1 = __builtin_amdgcn_mfma_f32_16x16x32_f16(af1, bb, a1, 0, 0, 0);
                l1 = __builtin_amdgcn_mfma_f32_16x16x32_f16(af1, ones, l1, 0, 0, 0);
            }
        }
    }
#pragma unroll
    for (int reg = 0; reg < 4; ++reg) {
        accred[wv][quad * 4 + reg][m] = a0[reg];
        accred[wv][quad * 4 + reg + 16][m] = a1[reg];
    }
    if (m == 0) {
#pragma unroll
        for (int reg = 0; reg < 4; ++reg) {
            lred[wv][quad * 4 + reg] = l0[reg];
            lred[wv][quad * 4 + reg + 16] = l1[reg];
        }
    }
    __syncthreads();
    const int row = tid >> 4, col = tid & 15;        // 512 threads = 32 rows x 16 cols
    float s = 0.f, l = 0.f;
#pragma unroll
    for (int w = 0; w < 8; ++w) { s += accred[w][row][col]; l += lred[w][row]; }
    float v = s / fmaxf(l, 1e-30f);
    out[((size_t)b * N_ + i0 + row) * EN_ + col] = v > 0.f ? v : expm1f(v);
}

extern "C" void kernel_launch(void* const* d_in, const int* in_sizes, int n_in,
                              void* d_out, int out_size, void* d_ws, size_t ws_size,
                              hipStream_t stream)
{
    const float* fea = (const float*)d_in[0];
    const float* adj = (const float*)d_in[1];
    const float* Wh  = (const float*)d_in[2];
    const float* ah  = (const float*)d_in[3];
    const float* Wl  = (const float*)d_in[4];
    const float* al  = (const float*)d_in[5];

    float* p = (float*)d_ws;
    float* wh1   = p;  p += (size_t)B_ * H_ * N_;            // 32768
    float* wh2   = p;  p += (size_t)B_ * H_ * N_;            // 32768
    float* wh1b  = p;  p += (size_t)B_ * N_;                 // 8192
    float* wh2b  = p;  p += (size_t)B_ * N_;                 // 8192
    float* cmax1 = p;  p += (size_t)B_ * H_ * 128;           // 1024
    float* cmax2 = p;  p += (size_t)B_ * 256;                // 512
    float* l1p   = p;  p += (size_t)S1_ * B_ * N_ * H_;      // 131072
    float* x2p   = p;  p += (size_t)S1_ * B_ * N_ * D_;      // 4194304
    unsigned long long* mask = (unsigned long long*)p;       // B*N*64 u64 = 4 MB
    unsigned short* whTt  = (unsigned short*)(mask + (size_t)B_ * N_ * 64);  // 2 MB
    unsigned short* whT2t = whTt + (size_t)B_ * H_ * 131072;                 // 256 KB

    prep_kernel<<<2048 + B_ * H_ * 128, 256, 0, stream>>>(adj, mask, fea, Wh, ah,
                                                          wh1, wh2, cmax1, whTt);
    attn1_kernel<<<dim3(N_ / 32, S1_, B_), 256, 0, stream>>>(mask, whTt, wh1, wh2, cmax1,
                                                             x2p, l1p);
    proj2_kernel<<<dim3(N_ / 16, B_), 256, 0, stream>>>(x2p, l1p, Wl, al,
                                                        wh1b, wh2b, cmax2, whT2t);
    attn2f_kernel<<<dim3(N_ / 32, B_), 512, 0, stream>>>(mask, whT2t, wh1b, wh2b, cmax2,
                                                         (float*)d_out);
}